// Round 1
// 561.278 us; speedup vs baseline: 1.1519x; 1.1519x over previous
//
#include <hip/hip_runtime.h>

// DynamicRouting: grouped 1x1 conv (G=8, FI=FO=64) + 3-iter sigmoid routing.
// One 256-thread WG per (b,h) row of 64 pixels.
// Thread = (pixel p = tid&63, fo-quarter q = tid>>6); con[8][16] in VGPRs.
//
// v2: latency fix.
//  - x staged to LDS via global_load_lds width=16, double-buffered 8KB chunks
//    (32 channels each, 16 chunks). 2-phase pipeline: STAGE(c+1); compute(c);
//    __syncthreads() -- the barrier's vmcnt(0) drain sits AFTER ~1k cycles of
//    FMA, hiding HBM/L3 latency in-wave. 32 gload_lds/thread replaces 512
//    scalar global loads.
//  - packed fp32 (v_pk_fma_f32) over channel pairs: LDS float2 reads x
//    contiguous weight pairs (SGPR-pair operand), two independent acc chains.
//  - staging buffers (16KB) unioned with routing scratch (12KB).

#define NG 8
#define NFO 64
#define NFI 64
#define NB 32
#define NH 64
#define NW 64
#define HW (NH * NW)

typedef float v2f __attribute__((ext_vector_type(2)));

__device__ __forceinline__ void stage_piece(const float* gsrc, float* ldst) {
    // wave-uniform ldst; HW writes lane L's 16B at ldst + L*16
    __builtin_amdgcn_global_load_lds(
        (const __attribute__((address_space(1))) void*)gsrc,
        (__attribute__((address_space(3))) void*)ldst, 16, 0, 0);
}

__global__ __launch_bounds__(256) void dynrout_kernel(
    const float* __restrict__ x, const float* __restrict__ weight,
    const float* __restrict__ bias, float* __restrict__ out)
{
    const int tid = threadIdx.x;
    const int p = tid & 63;
    const int q = __builtin_amdgcn_readfirstlane(tid >> 6);  // fo-quarter, wave-uniform

    const int wg = blockIdx.x;
    const int b = wg >> 6;
    const int h = wg & 63;

    __shared__ __align__(16) float smem[4096];  // 16 KiB: 2x8KB staging, reused for routing

    const float* xrow = x + (size_t)b * (NG * NFI) * HW + (size_t)h * NW;
    // per-lane source inside a 4-channel (1KB) piece: lane L -> ch +(L>>4), px (L&15)*4
    const float* gpiece = xrow + (size_t)(p >> 4) * HW + (size_t)(p & 15) * 4;

    float con[8][16];
#pragma unroll
    for (int g = 0; g < 8; ++g)
#pragma unroll
        for (int f = 0; f < 16; ++f) con[g][f] = 0.f;

    // ---- prologue: stage chunk 0 (channels 0..31) into buf0 ----
    {
        float* dst = smem;  // buf0
        const float* g0 = gpiece;
        stage_piece(g0 + (size_t)(q * 8) * HW,       dst + (q * 2) * 256);
        stage_piece(g0 + (size_t)(q * 8 + 4) * HW,   dst + (q * 2 + 1) * 256);
    }
    __syncthreads();

    // ---- main loop: chunk c = channels [c*32, c*32+32), group g = c>>1 ----
#pragma unroll
    for (int c = 0; c < 16; ++c) {
        if (c < 15) {
            float* dst = smem + ((c + 1) & 1) * 2048;
            const float* g0 = gpiece + (size_t)((c + 1) * 32) * HW;
            stage_piece(g0 + (size_t)(q * 8) * HW,     dst + (q * 2) * 256);
            stage_piece(g0 + (size_t)(q * 8 + 4) * HW, dst + (q * 2 + 1) * 256);
        }

        const int g = c >> 1;
        const float* bufp = smem + (c & 1) * 2048;  // [32 ch][64 px]

        v2f xp[16];
#pragma unroll
        for (int jp = 0; jp < 16; ++jp) {
            xp[jp].x = bufp[(2 * jp) * 64 + p];
            xp[jp].y = bufp[(2 * jp + 1) * 64 + p];
        }

        const float* wq = weight + ((size_t)g * NFO + (size_t)q * 16) * NFI + (c & 1) * 32;
#pragma unroll
        for (int f = 0; f < 16; ++f) {
            const float* wr = wq + (size_t)f * NFI;
            v2f a0 = {0.f, 0.f}, a1 = {0.f, 0.f};
#pragma unroll
            for (int jp = 0; jp < 16; jp += 2) {
                const v2f w0 = *(const v2f*)(wr + 2 * jp);
                const v2f w1 = *(const v2f*)(wr + 2 * jp + 2);
                a0 = __builtin_elementwise_fma(w0, xp[jp], a0);
                a1 = __builtin_elementwise_fma(w1, xp[jp + 1], a1);
            }
            con[g][f] += (a0.x + a1.x) + (a0.y + a1.y);
        }
        __syncthreads();  // drains vmcnt(0): chunk c+1 staged; buf[c&1] free to overwrite
    }

    // ---- routing (unchanged math; scratch unioned into smem) ----
    float* pbuf   = smem;          // [4][8][64] partial beta sums (overlaps dead buf0)
    float* alphaS = smem + 2048;   // [8][64]    (overlaps dead buf1)
    float* betaS  = smem + 2560;   // [8][64]

    float v[16];

    // iter 0: alpha = sigmoid(0) = 0.5; v0 = 0.5 * sum_g con
#pragma unroll
    for (int f = 0; f < 16; ++f) {
        float s = con[0][f];
#pragma unroll
        for (int g = 1; g < 8; ++g) s += con[g][f];
        v[f] = 0.5f * s;
    }
#pragma unroll
    for (int g = 0; g < 8; ++g) {
        float s = 0.f;
#pragma unroll
        for (int f = 0; f < 16; ++f) s = fmaf(v[f], con[g][f], s);
        pbuf[(q * 8 + g) * 64 + p] = s;
    }
    __syncthreads();
    for (int k = tid; k < 512; k += 256) {
        const int gg = k >> 6, pp = k & 63;
        const float bs = pbuf[gg * 64 + pp] + pbuf[512 + gg * 64 + pp] +
                         pbuf[1024 + gg * 64 + pp] + pbuf[1536 + gg * 64 + pp];
        betaS[gg * 64 + pp] = bs;
        alphaS[gg * 64 + pp] = 1.f / (1.f + __expf(-bs));
    }
    __syncthreads();

    // iter 1: v1 = sum_g alpha1*con; beta2 partials
    float a[8];
#pragma unroll
    for (int g = 0; g < 8; ++g) a[g] = alphaS[g * 64 + p];
#pragma unroll
    for (int f = 0; f < 16; ++f) {
        float s = 0.f;
#pragma unroll
        for (int g = 0; g < 8; ++g) s = fmaf(a[g], con[g][f], s);
        v[f] = s;
    }
#pragma unroll
    for (int g = 0; g < 8; ++g) {
        float s = 0.f;
#pragma unroll
        for (int f = 0; f < 16; ++f) s = fmaf(v[f], con[g][f], s);
        pbuf[(q * 8 + g) * 64 + p] = s;
    }
    __syncthreads();
    for (int k = tid; k < 512; k += 256) {
        const int gg = k >> 6, pp = k & 63;
        const float bs = betaS[gg * 64 + pp] +
                         pbuf[gg * 64 + pp] + pbuf[512 + gg * 64 + pp] +
                         pbuf[1024 + gg * 64 + pp] + pbuf[1536 + gg * 64 + pp];
        alphaS[gg * 64 + pp] = 1.f / (1.f + __expf(-bs));
    }
    __syncthreads();

    // iter 2: out = sum_g alpha2*con + bias
#pragma unroll
    for (int g = 0; g < 8; ++g) a[g] = alphaS[g * 64 + p];

    const float* bq = bias + q * 16;
    float* orow = out + (((size_t)b * NFO + (size_t)q * 16) * NH + h) * NW + p;
#pragma unroll
    for (int f = 0; f < 16; ++f) {
        float s = bq[f];
#pragma unroll
        for (int g = 0; g < 8; ++g) s = fmaf(a[g], con[g][f], s);
        orow[(size_t)f * HW] = s;
    }
}

extern "C" void kernel_launch(void* const* d_in, const int* in_sizes, int n_in,
                              void* d_out, int out_size, void* d_ws, size_t ws_size,
                              hipStream_t stream) {
    const float* x      = (const float*)d_in[0];
    const float* weight = (const float*)d_in[1];
    const float* bias   = (const float*)d_in[2];
    float* out = (float*)d_out;

    dynrout_kernel<<<dim3(NB * NH), dim3(256), 0, stream>>>(x, weight, bias, out);
}